// Round 1
// baseline (702.686 us; speedup 1.0000x reference)
//
#include <hip/hip_runtime.h>
#include <hip/hip_bf16.h>
#include <cstdint>

// Problem constants
#define D_DIM  2048
#define T_DIM  4096
#define B_DIM  2
#define M_DIM  8192   // B*T
#define DG_DIM 2048
#define N2_DIM 8192   // D*W (W=4)
#define K_DIM  2048

typedef __bf16 bf16x8 __attribute__((ext_vector_type(8)));
typedef __bf16 bf16x4 __attribute__((ext_vector_type(4)));
typedef float  f32x4  __attribute__((ext_vector_type(4)));

__device__ __forceinline__ void gload_lds16(const void* g, void* l) {
  __builtin_amdgcn_global_load_lds(
      (__attribute__((address_space(1))) void*)g,
      (__attribute__((address_space(3))) void*)l, 16, 0, 0);
}

__device__ __forceinline__ float silu_f(float a) {
  return a / (1.f + __expf(-a));
}

// fp32 -> bf16 cast, float4 / bf16x4 vectorized
__global__ void cast_f32_bf16(const float* __restrict__ src,
                              __bf16* __restrict__ dst, int n4) {
  int i = blockIdx.x * blockDim.x + threadIdx.x;
  if (i >= n4) return;
  float4 v = ((const float4*)src)[i];
  bf16x4 o;
  o[0] = (__bf16)v.x; o[1] = (__bf16)v.y; o[2] = (__bf16)v.z; o[3] = (__bf16)v.w;
  ((bf16x4*)dst)[i] = o;
}

// ---------------------------------------------------------------------------
// GEMM1: H[m][n] = silu( sum_k A[m][k] * B[n][k] )   A=x_bf16, B=w1_bf16
// 128x128 tile, BK=32, 4 waves (2x2 of 64x64), mfma_f32_16x16x32_bf16
// ---------------------------------------------------------------------------
__global__ __launch_bounds__(256) void gemm1_silu(
    const __bf16* __restrict__ A, const __bf16* __restrict__ B,
    __bf16* __restrict__ H) {
  constexpr int K = K_DIM, N = DG_DIM;
  __shared__ __bf16 sA[128 * 32];
  __shared__ __bf16 sB[128 * 32];
  const int tid  = threadIdx.x;
  const int lane = tid & 63;
  const int wv   = tid >> 6;
  const int wm   = wv >> 1, wn = wv & 1;
  const int ln   = lane & 15, qd = lane >> 4;
  const int m0 = blockIdx.y * 128, n0 = blockIdx.x * 128;

  f32x4 acc[4][4] = {};

  const int c0 = tid, c1 = tid + 256;
  const int r0 = c0 >> 2, kc0 = (c0 & 3) * 8;
  const int r1 = c1 >> 2, kc1 = (c1 & 3) * 8;
  const __bf16* gA0 = A + (size_t)(m0 + r0) * K + kc0;
  const __bf16* gA1 = A + (size_t)(m0 + r1) * K + kc1;
  const __bf16* gB0 = B + (size_t)(n0 + r0) * K + kc0;
  const __bf16* gB1 = B + (size_t)(n0 + r1) * K + kc1;

  for (int k0 = 0; k0 < K; k0 += 32) {
    gload_lds16(gA0 + k0, sA + c0 * 8);
    gload_lds16(gA1 + k0, sA + c1 * 8);
    gload_lds16(gB0 + k0, sB + c0 * 8);
    gload_lds16(gB1 + k0, sB + c1 * 8);
    __syncthreads();
    bf16x8 af[4], bfr[4];
#pragma unroll
    for (int i = 0; i < 4; i++)
      af[i] = *(const bf16x8*)(sA + (wm * 64 + i * 16 + ln) * 32 + qd * 8);
#pragma unroll
    for (int j = 0; j < 4; j++)
      bfr[j] = *(const bf16x8*)(sB + (wn * 64 + j * 16 + ln) * 32 + qd * 8);
#pragma unroll
    for (int i = 0; i < 4; i++)
#pragma unroll
      for (int j = 0; j < 4; j++)
        acc[i][j] = __builtin_amdgcn_mfma_f32_16x16x32_bf16(af[i], bfr[j],
                                                            acc[i][j], 0, 0, 0);
    __syncthreads();
  }

  // epilogue: silu -> bf16.  C layout: row=(lane>>4)*4+reg, col=lane&15
#pragma unroll
  for (int i = 0; i < 4; i++) {
#pragma unroll
    for (int j = 0; j < 4; j++) {
      const int col = n0 + wn * 64 + j * 16 + ln;
#pragma unroll
      for (int r = 0; r < 4; r++) {
        const int row = m0 + wm * 64 + i * 16 + qd * 4 + r;
        H[(size_t)row * N + col] = (__bf16)silu_f(acc[i][j][r]);
      }
    }
  }
}

// ---------------------------------------------------------------------------
// GEMM2 + fused conv: flat[m][k] = sum A[m][:]B[k][:] + b2[k]; k = 4*d + w
// y[m][d] = sum_w flat[m][4d+w] * x[b, t+w-3, d];  out = silu(y)
// A = h_bf16, B = w2_bf16, x fp32 original input.
// ---------------------------------------------------------------------------
__global__ __launch_bounds__(256) void gemm2_conv_silu(
    const __bf16* __restrict__ A, const __bf16* __restrict__ B,
    const float* __restrict__ b2, const float* __restrict__ x,
    float* __restrict__ out) {
  constexpr int K = K_DIM;
  __shared__ __bf16 sA[128 * 32];
  __shared__ __bf16 sB[128 * 32];
  const int tid  = threadIdx.x;
  const int lane = tid & 63;
  const int wv   = tid >> 6;
  const int wm   = wv >> 1, wn = wv & 1;
  const int ln   = lane & 15, qd = lane >> 4;
  const int m0 = blockIdx.y * 128, n0 = blockIdx.x * 128;

  f32x4 acc[4][4] = {};

  const int c0 = tid, c1 = tid + 256;
  const int r0 = c0 >> 2, kc0 = (c0 & 3) * 8;
  const int r1 = c1 >> 2, kc1 = (c1 & 3) * 8;
  const __bf16* gA0 = A + (size_t)(m0 + r0) * K + kc0;
  const __bf16* gA1 = A + (size_t)(m0 + r1) * K + kc1;
  const __bf16* gB0 = B + (size_t)(n0 + r0) * K + kc0;
  const __bf16* gB1 = B + (size_t)(n0 + r1) * K + kc1;

  for (int k0 = 0; k0 < K; k0 += 32) {
    gload_lds16(gA0 + k0, sA + c0 * 8);
    gload_lds16(gA1 + k0, sA + c1 * 8);
    gload_lds16(gB0 + k0, sB + c0 * 8);
    gload_lds16(gB1 + k0, sB + c1 * 8);
    __syncthreads();
    bf16x8 af[4], bfr[4];
#pragma unroll
    for (int i = 0; i < 4; i++)
      af[i] = *(const bf16x8*)(sA + (wm * 64 + i * 16 + ln) * 32 + qd * 8);
#pragma unroll
    for (int j = 0; j < 4; j++)
      bfr[j] = *(const bf16x8*)(sB + (wn * 64 + j * 16 + ln) * 32 + qd * 8);
#pragma unroll
    for (int i = 0; i < 4; i++)
#pragma unroll
      for (int j = 0; j < 4; j++)
        acc[i][j] = __builtin_amdgcn_mfma_f32_16x16x32_bf16(af[i], bfr[j],
                                                            acc[i][j], 0, 0, 0);
    __syncthreads();
  }

  // Fused epilogue. Lane's column k = n0+wn*64+j*16+ln; d = k>>2, w = k&3 = ln&3.
  // Taps w=0..3 of one d live in lanes {g,g+1,g+2,g+3}; butterfly-sum them.
  float b2v[4];
#pragma unroll
  for (int j = 0; j < 4; j++) b2v[j] = b2[n0 + wn * 64 + j * 16 + ln];
  const int w_tap = ln & 3;

#pragma unroll
  for (int i = 0; i < 4; i++) {
#pragma unroll
    for (int r = 0; r < 4; r++) {
      const int m_g = m0 + wm * 64 + i * 16 + qd * 4 + r;
      const int b   = m_g >> 12;        // T=4096
      const int t   = m_g & 4095;
      const int tp  = t + w_tap - 3;    // causal tap position
      const float* xrow = x + ((size_t)((b << 12) + tp)) * D_DIM;
#pragma unroll
      for (int j = 0; j < 4; j++) {
        const int col = n0 + wn * 64 + j * 16 + ln;
        const int d   = col >> 2;
        float fv = acc[i][j][r] + b2v[j];
        float xv = (tp >= 0) ? xrow[d] : 0.f;
        float p  = fv * xv;
        p += __shfl_xor(p, 1);
        p += __shfl_xor(p, 2);
        if ((ln & 3) == 0) {
          out[(size_t)m_g * D_DIM + d] = silu_f(p);
        }
      }
    }
  }
}

extern "C" void kernel_launch(void* const* d_in, const int* in_sizes, int n_in,
                              void* d_out, int out_size, void* d_ws, size_t ws_size,
                              hipStream_t stream) {
  (void)in_sizes; (void)n_in; (void)out_size; (void)ws_size;
  const float* x  = (const float*)d_in[0];
  const float* w1 = (const float*)d_in[1];
  const float* w2 = (const float*)d_in[2];
  const float* b2 = (const float*)d_in[3];
  float* out = (float*)d_out;

  __bf16* xb  = (__bf16*)d_ws;                        // 8192*2048
  __bf16* w1b = xb  + (size_t)M_DIM * D_DIM;          // 2048*2048
  __bf16* w2b = w1b + (size_t)DG_DIM * D_DIM;         // 8192*2048
  __bf16* hb  = w2b + (size_t)N2_DIM * DG_DIM;        // 8192*2048

  {
    int n4 = M_DIM * D_DIM / 4;
    cast_f32_bf16<<<(n4 + 255) / 256, 256, 0, stream>>>(x, xb, n4);
  }
  {
    int n4 = DG_DIM * D_DIM / 4;
    cast_f32_bf16<<<(n4 + 255) / 256, 256, 0, stream>>>(w1, w1b, n4);
  }
  {
    int n4 = N2_DIM * DG_DIM / 4;
    cast_f32_bf16<<<(n4 + 255) / 256, 256, 0, stream>>>(w2, w2b, n4);
  }

  gemm1_silu<<<dim3(DG_DIM / 128, M_DIM / 128), 256, 0, stream>>>(xb, w1b, hb);
  gemm2_conv_silu<<<dim3(N2_DIM / 128, M_DIM / 128), 256, 0, stream>>>(
      hb, w2b, b2, x, out);
}

// Round 2
// 594.098 us; speedup vs baseline: 1.1828x; 1.1828x over previous
//
#include <hip/hip_runtime.h>
#include <hip/hip_bf16.h>
#include <cstdint>

// Problem constants
#define D_DIM  2048
#define T_DIM  4096
#define B_DIM  2
#define M_DIM  8192   // B*T
#define DG_DIM 2048
#define N2_DIM 8192   // D*W (W=4)
#define K_DIM  2048

typedef __bf16 bf16x8 __attribute__((ext_vector_type(8)));
typedef __bf16 bf16x4 __attribute__((ext_vector_type(4)));
typedef float  f32x4  __attribute__((ext_vector_type(4)));

__device__ __forceinline__ void gload_lds16(const void* g, void* l) {
  __builtin_amdgcn_global_load_lds(
      (__attribute__((address_space(1))) void*)g,
      (__attribute__((address_space(3))) void*)l, 16, 0, 0);
}

__device__ __forceinline__ float silu_f(float a) {
  return a / (1.f + __expf(-a));
}

// fp32 -> bf16 cast, float4 / bf16x4 vectorized
__global__ void cast_f32_bf16(const float* __restrict__ src,
                              __bf16* __restrict__ dst, int n4) {
  int i = blockIdx.x * blockDim.x + threadIdx.x;
  if (i >= n4) return;
  float4 v = ((const float4*)src)[i];
  bf16x4 o;
  o[0] = (__bf16)v.x; o[1] = (__bf16)v.y; o[2] = (__bf16)v.z; o[3] = (__bf16)v.w;
  ((bf16x4*)dst)[i] = o;
}

// fp32 -> bf16 cast of w2 with ROW PERMUTATION so that GEMM2 column c holds
// original row k = 4*(32*(c>>7) + 16*wn + ln) + j, where within c&127:
// wn=(c>>6)&1, j=(c>>4)&3, ln=c&15. Then in the MFMA C-layout each lane's
// four j-accumulators are the 4 taps (w=0..3) of one d.
__global__ void cast_permute_w2(const float* __restrict__ src,
                                __bf16* __restrict__ dst, int n4) {
  int i = blockIdx.x * blockDim.x + threadIdx.x;
  if (i >= n4) return;
  const int row = i >> 9;            // dest row c (512 float4 per row of 2048)
  const int pos = i & 511;
  const int blk = row >> 7, within = row & 127;
  const int wn = (within >> 6) & 1, j = (within >> 4) & 3, ln = within & 15;
  const int d = blk * 32 + wn * 16 + ln;
  const int k = 4 * d + j;           // original w2 row
  float4 v = ((const float4*)src)[(size_t)k * 512 + pos];
  bf16x4 o;
  o[0] = (__bf16)v.x; o[1] = (__bf16)v.y; o[2] = (__bf16)v.z; o[3] = (__bf16)v.w;
  ((bf16x4*)dst)[i] = o;
}

// ---------------------------------------------------------------------------
// GEMM1: H[m][n] = silu( sum_k A[m][k] * B[n][k] )   A=x_bf16, B=w1_bf16
// 128x128 tile, BK=32, 4 waves (2x2 of 64x64), mfma_f32_16x16x32_bf16
// ---------------------------------------------------------------------------
__global__ __launch_bounds__(256) void gemm1_silu(
    const __bf16* __restrict__ A, const __bf16* __restrict__ B,
    __bf16* __restrict__ H) {
  constexpr int K = K_DIM, N = DG_DIM;
  __shared__ __bf16 sA[128 * 32];
  __shared__ __bf16 sB[128 * 32];
  const int tid  = threadIdx.x;
  const int lane = tid & 63;
  const int wv   = tid >> 6;
  const int wm   = wv >> 1, wn = wv & 1;
  const int ln   = lane & 15, qd = lane >> 4;
  const int m0 = blockIdx.y * 128, n0 = blockIdx.x * 128;

  f32x4 acc[4][4] = {};

  const int c0 = tid, c1 = tid + 256;
  const int r0 = c0 >> 2, kc0 = (c0 & 3) * 8;
  const int r1 = c1 >> 2, kc1 = (c1 & 3) * 8;
  const __bf16* gA0 = A + (size_t)(m0 + r0) * K + kc0;
  const __bf16* gA1 = A + (size_t)(m0 + r1) * K + kc1;
  const __bf16* gB0 = B + (size_t)(n0 + r0) * K + kc0;
  const __bf16* gB1 = B + (size_t)(n0 + r1) * K + kc1;

  for (int k0 = 0; k0 < K; k0 += 32) {
    gload_lds16(gA0 + k0, sA + c0 * 8);
    gload_lds16(gA1 + k0, sA + c1 * 8);
    gload_lds16(gB0 + k0, sB + c0 * 8);
    gload_lds16(gB1 + k0, sB + c1 * 8);
    __syncthreads();
    bf16x8 af[4], bfr[4];
#pragma unroll
    for (int i = 0; i < 4; i++)
      af[i] = *(const bf16x8*)(sA + (wm * 64 + i * 16 + ln) * 32 + qd * 8);
#pragma unroll
    for (int j = 0; j < 4; j++)
      bfr[j] = *(const bf16x8*)(sB + (wn * 64 + j * 16 + ln) * 32 + qd * 8);
#pragma unroll
    for (int i = 0; i < 4; i++)
#pragma unroll
      for (int j = 0; j < 4; j++)
        acc[i][j] = __builtin_amdgcn_mfma_f32_16x16x32_bf16(af[i], bfr[j],
                                                            acc[i][j], 0, 0, 0);
    __syncthreads();
  }

  // epilogue: silu -> bf16.  C layout: row=(lane>>4)*4+reg, col=lane&15
#pragma unroll
  for (int i = 0; i < 4; i++) {
#pragma unroll
    for (int j = 0; j < 4; j++) {
      const int col = n0 + wn * 64 + j * 16 + ln;
#pragma unroll
      for (int r = 0; r < 4; r++) {
        const int row = m0 + wm * 64 + i * 16 + qd * 4 + r;
        H[(size_t)row * N + col] = (__bf16)silu_f(acc[i][j][r]);
      }
    }
  }
}

// ---------------------------------------------------------------------------
// GEMM2 + fused conv. B is the PERMUTED w2 (see cast_permute_w2): GEMM column
// c holds flat[:, 4*d(c) + j(c)] with d = 32*(c>>7) + 16*wn + ln, j = tap.
// Each lane's 4 j-accumulators = the 4 taps of one d -> no cross-lane reduce.
// y[m][d] = sum_j (acc_j + b2[4d+j]) * x[b, t+j-3, d];  out = silu(y)
// ---------------------------------------------------------------------------
__global__ __launch_bounds__(256) void gemm2_conv_silu(
    const __bf16* __restrict__ A, const __bf16* __restrict__ B,
    const float* __restrict__ b2, const float* __restrict__ x,
    float* __restrict__ out) {
  constexpr int K = K_DIM;
  __shared__ __bf16 sA[128 * 32];
  __shared__ __bf16 sB[128 * 32];
  const int tid  = threadIdx.x;
  const int lane = tid & 63;
  const int wv   = tid >> 6;
  const int wm   = wv >> 1, wn = wv & 1;
  const int ln   = lane & 15, qd = lane >> 4;
  const int m0 = blockIdx.y * 128, n0 = blockIdx.x * 128;

  f32x4 acc[4][4] = {};

  const int c0 = tid, c1 = tid + 256;
  const int r0 = c0 >> 2, kc0 = (c0 & 3) * 8;
  const int r1 = c1 >> 2, kc1 = (c1 & 3) * 8;
  const __bf16* gA0 = A + (size_t)(m0 + r0) * K + kc0;
  const __bf16* gA1 = A + (size_t)(m0 + r1) * K + kc1;
  const __bf16* gB0 = B + (size_t)(n0 + r0) * K + kc0;
  const __bf16* gB1 = B + (size_t)(n0 + r1) * K + kc1;

  for (int k0 = 0; k0 < K; k0 += 32) {
    gload_lds16(gA0 + k0, sA + c0 * 8);
    gload_lds16(gA1 + k0, sA + c1 * 8);
    gload_lds16(gB0 + k0, sB + c0 * 8);
    gload_lds16(gB1 + k0, sB + c1 * 8);
    __syncthreads();
    bf16x8 af[4], bfr[4];
#pragma unroll
    for (int i = 0; i < 4; i++)
      af[i] = *(const bf16x8*)(sA + (wm * 64 + i * 16 + ln) * 32 + qd * 8);
#pragma unroll
    for (int j = 0; j < 4; j++)
      bfr[j] = *(const bf16x8*)(sB + (wn * 64 + j * 16 + ln) * 32 + qd * 8);
#pragma unroll
    for (int i = 0; i < 4; i++)
#pragma unroll
      for (int j = 0; j < 4; j++)
        acc[i][j] = __builtin_amdgcn_mfma_f32_16x16x32_bf16(af[i], bfr[j],
                                                            acc[i][j], 0, 0, 0);
    __syncthreads();
  }

  // Fused epilogue, no shuffles: this lane owns d = 32*(n0>>7)+16*wn+ln,
  // taps j=0..3 in acc[i][j][r].
  const int d = (n0 >> 2) + wn * 16 + ln;
  const float4 bias = *(const float4*)(b2 + 4 * d);

#pragma unroll
  for (int i = 0; i < 4; i++) {
    const int m_base = m0 + wm * 64 + i * 16 + qd * 4;   // + r
    const int b  = m_base >> 12;                          // T=4096
    const int tb = m_base & 4095;
    // taps needed: x[b, tb + s - 3, d] for s = r + j in [0,6]
    float xv[7];
#pragma unroll
    for (int s = 0; s < 7; s++) {
      const int tp = tb + s - 3;
      xv[s] = (tp >= 0) ? x[((size_t)((b << 12) + tp)) * D_DIM + d] : 0.f;
    }
#pragma unroll
    for (int r = 0; r < 4; r++) {
      float y = (acc[i][0][r] + bias.x) * xv[r + 0]
              + (acc[i][1][r] + bias.y) * xv[r + 1]
              + (acc[i][2][r] + bias.z) * xv[r + 2]
              + (acc[i][3][r] + bias.w) * xv[r + 3];
      out[(size_t)(m_base + r) * D_DIM + d] = silu_f(y);
    }
  }
}

extern "C" void kernel_launch(void* const* d_in, const int* in_sizes, int n_in,
                              void* d_out, int out_size, void* d_ws, size_t ws_size,
                              hipStream_t stream) {
  (void)in_sizes; (void)n_in; (void)out_size; (void)ws_size;
  const float* x  = (const float*)d_in[0];
  const float* w1 = (const float*)d_in[1];
  const float* w2 = (const float*)d_in[2];
  const float* b2 = (const float*)d_in[3];
  float* out = (float*)d_out;

  __bf16* xb  = (__bf16*)d_ws;                        // 8192*2048
  __bf16* w1b = xb  + (size_t)M_DIM * D_DIM;          // 2048*2048
  __bf16* w2b = w1b + (size_t)DG_DIM * D_DIM;         // 8192*2048 (permuted)
  __bf16* hb  = w2b + (size_t)N2_DIM * DG_DIM;        // 8192*2048

  {
    int n4 = M_DIM * D_DIM / 4;
    cast_f32_bf16<<<(n4 + 255) / 256, 256, 0, stream>>>(x, xb, n4);
  }
  {
    int n4 = DG_DIM * D_DIM / 4;
    cast_f32_bf16<<<(n4 + 255) / 256, 256, 0, stream>>>(w1, w1b, n4);
  }
  {
    int n4 = N2_DIM * DG_DIM / 4;
    cast_permute_w2<<<(n4 + 255) / 256, 256, 0, stream>>>(w2, w2b, n4);
  }

  gemm1_silu<<<dim3(DG_DIM / 128, M_DIM / 128), 256, 0, stream>>>(xb, w1b, hb);
  gemm2_conv_silu<<<dim3(N2_DIM / 128, M_DIM / 128), 256, 0, stream>>>(
      hb, w2b, b2, x, out);
}

// Round 3
// 537.708 us; speedup vs baseline: 1.3068x; 1.1049x over previous
//
#include <hip/hip_runtime.h>
#include <hip/hip_bf16.h>
#include <cstdint>

// Problem constants
#define D_DIM  2048
#define T_DIM  4096
#define B_DIM  2
#define M_DIM  8192   // B*T
#define DG_DIM 2048
#define N2_DIM 8192   // D*W (W=4)
#define K_DIM  2048

typedef __bf16 bf16x8 __attribute__((ext_vector_type(8)));
typedef __bf16 bf16x4 __attribute__((ext_vector_type(4)));
typedef float  f32x4  __attribute__((ext_vector_type(4)));

__device__ __forceinline__ void gload_lds16(const void* g, void* l) {
  __builtin_amdgcn_global_load_lds(
      (__attribute__((address_space(1))) void*)g,
      (__attribute__((address_space(3))) void*)l, 16, 0, 0);
}

__device__ __forceinline__ float silu_f(float a) {
  return a / (1.f + __expf(-a));
}

// fp32 -> bf16 cast, float4 / bf16x4 vectorized
__global__ void cast_f32_bf16(const float* __restrict__ src,
                              __bf16* __restrict__ dst, int n4) {
  int i = blockIdx.x * blockDim.x + threadIdx.x;
  if (i >= n4) return;
  float4 v = ((const float4*)src)[i];
  bf16x4 o;
  o[0] = (__bf16)v.x; o[1] = (__bf16)v.y; o[2] = (__bf16)v.z; o[3] = (__bf16)v.w;
  ((bf16x4*)dst)[i] = o;
}

// fp32 -> bf16 cast of w2 with ROW PERMUTATION so that GEMM2 column c holds
// original row k = 4*(32*(c>>7) + 16*wn + ln) + j. Then in the MFMA C-layout
// each lane's four j-accumulators are the 4 taps (w=0..3) of one d.
__global__ void cast_permute_w2(const float* __restrict__ src,
                                __bf16* __restrict__ dst, int n4) {
  int i = blockIdx.x * blockDim.x + threadIdx.x;
  if (i >= n4) return;
  const int row = i >> 9;            // dest row c (512 float4 per row of 2048)
  const int pos = i & 511;
  const int blk = row >> 7, within = row & 127;
  const int wn = (within >> 6) & 1, j = (within >> 4) & 3, ln = within & 15;
  const int d = blk * 32 + wn * 16 + ln;
  const int k = 4 * d + j;           // original w2 row
  float4 v = ((const float4*)src)[(size_t)k * 512 + pos];
  bf16x4 o;
  o[0] = (__bf16)v.x; o[1] = (__bf16)v.y; o[2] = (__bf16)v.z; o[3] = (__bf16)v.w;
  ((bf16x4*)dst)[i] = o;
}

// ---------------------------------------------------------------------------
// Shared K-loop structure: 128x128 tile, BK=64, XOR-swizzled LDS.
// LDS row r (8 chunks of 16B): global chunk c stored at slot (c ^ (r&7)).
// Staging lane mapping (per wave wv, inst): g=lane>>3, cl=lane&7,
//   r=(inst*4+wv)*8+g, fetched global chunk = cl ^ g  -> dest base+lane*16.
// Read: row's chunk c at element offset r*64 + ((c ^ (r&7))*8).
// A 16-lane read phase spreads over all 32 banks (only free 2-way aliasing).
// ---------------------------------------------------------------------------

// GEMM1: H[m][n] = silu( sum_k A[m][k] * B[n][k] )   A=x_bf16, B=w1_bf16
__global__ __launch_bounds__(256) void gemm1_silu(
    const __bf16* __restrict__ A, const __bf16* __restrict__ B,
    __bf16* __restrict__ H) {
  constexpr int K = K_DIM, N = DG_DIM;
  __shared__ __bf16 sA[128 * 64];
  __shared__ __bf16 sB[128 * 64];
  const int tid  = threadIdx.x;
  const int lane = tid & 63;
  const int wv   = tid >> 6;
  const int wm   = wv >> 1, wn = wv & 1;
  const int ln   = lane & 15, qd = lane >> 4;
  const int m0 = blockIdx.y * 128, n0 = blockIdx.x * 128;

  f32x4 acc[4][4] = {};

  const int g  = lane >> 3;
  const int cl = lane & 7;
  const int cg = cl ^ g;                 // global chunk this lane fetches
  const __bf16* gA[4];
  const __bf16* gB[4];
  int loff[4];
#pragma unroll
  for (int inst = 0; inst < 4; inst++) {
    const int r = (inst * 4 + wv) * 8 + g;
    gA[inst]   = A + (size_t)(m0 + r) * K + cg * 8;
    gB[inst]   = B + (size_t)(n0 + r) * K + cg * 8;
    loff[inst] = ((inst * 4 + wv) * 64 + lane) * 8;
  }

  for (int k0 = 0; k0 < K; k0 += 64) {
#pragma unroll
    for (int inst = 0; inst < 4; inst++)
      gload_lds16(gA[inst] + k0, sA + loff[inst]);
#pragma unroll
    for (int inst = 0; inst < 4; inst++)
      gload_lds16(gB[inst] + k0, sB + loff[inst]);
    __syncthreads();
#pragma unroll
    for (int h = 0; h < 2; h++) {
      bf16x8 af[4], bfr[4];
#pragma unroll
      for (int i = 0; i < 4; i++) {
        const int row = wm * 64 + i * 16 + ln;
        af[i] = *(const bf16x8*)(sA + row * 64 + (((h << 2) + qd) ^ (row & 7)) * 8);
      }
#pragma unroll
      for (int j = 0; j < 4; j++) {
        const int row = wn * 64 + j * 16 + ln;
        bfr[j] = *(const bf16x8*)(sB + row * 64 + (((h << 2) + qd) ^ (row & 7)) * 8);
      }
#pragma unroll
      for (int i = 0; i < 4; i++)
#pragma unroll
        for (int j = 0; j < 4; j++)
          acc[i][j] = __builtin_amdgcn_mfma_f32_16x16x32_bf16(af[i], bfr[j],
                                                              acc[i][j], 0, 0, 0);
    }
    __syncthreads();
  }

  // epilogue: silu -> bf16.  C layout: row=(lane>>4)*4+reg, col=lane&15
#pragma unroll
  for (int i = 0; i < 4; i++) {
#pragma unroll
    for (int j = 0; j < 4; j++) {
      const int col = n0 + wn * 64 + j * 16 + ln;
#pragma unroll
      for (int r = 0; r < 4; r++) {
        const int row = m0 + wm * 64 + i * 16 + qd * 4 + r;
        H[(size_t)row * N + col] = (__bf16)silu_f(acc[i][j][r]);
      }
    }
  }
}

// GEMM2 + fused conv. B is the PERMUTED w2: GEMM column c holds
// flat[:, 4*d(c) + j(c)] with d = 32*(c>>7) + 16*wn + ln, j = tap.
// y[m][d] = sum_j (acc_j + b2[4d+j]) * x[b, t+j-3, d];  out = silu(y)
__global__ __launch_bounds__(256) void gemm2_conv_silu(
    const __bf16* __restrict__ A, const __bf16* __restrict__ B,
    const float* __restrict__ b2, const float* __restrict__ x,
    float* __restrict__ out) {
  constexpr int K = K_DIM;
  __shared__ __bf16 sA[128 * 64];
  __shared__ __bf16 sB[128 * 64];
  const int tid  = threadIdx.x;
  const int lane = tid & 63;
  const int wv   = tid >> 6;
  const int wm   = wv >> 1, wn = wv & 1;
  const int ln   = lane & 15, qd = lane >> 4;
  const int m0 = blockIdx.y * 128, n0 = blockIdx.x * 128;

  f32x4 acc[4][4] = {};

  const int g  = lane >> 3;
  const int cl = lane & 7;
  const int cg = cl ^ g;
  const __bf16* gA[4];
  const __bf16* gB[4];
  int loff[4];
#pragma unroll
  for (int inst = 0; inst < 4; inst++) {
    const int r = (inst * 4 + wv) * 8 + g;
    gA[inst]   = A + (size_t)(m0 + r) * K + cg * 8;
    gB[inst]   = B + (size_t)(n0 + r) * K + cg * 8;
    loff[inst] = ((inst * 4 + wv) * 64 + lane) * 8;
  }

  for (int k0 = 0; k0 < K; k0 += 64) {
#pragma unroll
    for (int inst = 0; inst < 4; inst++)
      gload_lds16(gA[inst] + k0, sA + loff[inst]);
#pragma unroll
    for (int inst = 0; inst < 4; inst++)
      gload_lds16(gB[inst] + k0, sB + loff[inst]);
    __syncthreads();
#pragma unroll
    for (int h = 0; h < 2; h++) {
      bf16x8 af[4], bfr[4];
#pragma unroll
      for (int i = 0; i < 4; i++) {
        const int row = wm * 64 + i * 16 + ln;
        af[i] = *(const bf16x8*)(sA + row * 64 + (((h << 2) + qd) ^ (row & 7)) * 8);
      }
#pragma unroll
      for (int j = 0; j < 4; j++) {
        const int row = wn * 64 + j * 16 + ln;
        bfr[j] = *(const bf16x8*)(sB + row * 64 + (((h << 2) + qd) ^ (row & 7)) * 8);
      }
#pragma unroll
      for (int i = 0; i < 4; i++)
#pragma unroll
        for (int j = 0; j < 4; j++)
          acc[i][j] = __builtin_amdgcn_mfma_f32_16x16x32_bf16(af[i], bfr[j],
                                                              acc[i][j], 0, 0, 0);
    }
    __syncthreads();
  }

  // Fused epilogue, no shuffles: this lane owns d = 32*(n0>>7)+16*wn+ln,
  // taps j=0..3 in acc[i][j][r].
  const int d = (n0 >> 2) + wn * 16 + ln;
  const float4 bias = *(const float4*)(b2 + 4 * d);

#pragma unroll
  for (int i = 0; i < 4; i++) {
    const int m_base = m0 + wm * 64 + i * 16 + qd * 4;   // + r
    const int b  = m_base >> 12;                          // T=4096
    const int tb = m_base & 4095;
    // taps needed: x[b, tb + s - 3, d] for s = r + j in [0,6]
    float xv[7];
#pragma unroll
    for (int s = 0; s < 7; s++) {
      const int tp = tb + s - 3;
      xv[s] = (tp >= 0) ? x[((size_t)((b << 12) + tp)) * D_DIM + d] : 0.f;
    }
#pragma unroll
    for (int r = 0; r < 4; r++) {
      float y = (acc[i][0][r] + bias.x) * xv[r + 0]
              + (acc[i][1][r] + bias.y) * xv[r + 1]
              + (acc[i][2][r] + bias.z) * xv[r + 2]
              + (acc[i][3][r] + bias.w) * xv[r + 3];
      out[(size_t)(m_base + r) * D_DIM + d] = silu_f(y);
    }
  }
}

extern "C" void kernel_launch(void* const* d_in, const int* in_sizes, int n_in,
                              void* d_out, int out_size, void* d_ws, size_t ws_size,
                              hipStream_t stream) {
  (void)in_sizes; (void)n_in; (void)out_size; (void)ws_size;
  const float* x  = (const float*)d_in[0];
  const float* w1 = (const float*)d_in[1];
  const float* w2 = (const float*)d_in[2];
  const float* b2 = (const float*)d_in[3];
  float* out = (float*)d_out;

  __bf16* xb  = (__bf16*)d_ws;                        // 8192*2048
  __bf16* w1b = xb  + (size_t)M_DIM * D_DIM;          // 2048*2048
  __bf16* w2b = w1b + (size_t)DG_DIM * D_DIM;         // 8192*2048 (permuted)
  __bf16* hb  = w2b + (size_t)N2_DIM * DG_DIM;        // 8192*2048

  {
    int n4 = M_DIM * D_DIM / 4;
    cast_f32_bf16<<<(n4 + 255) / 256, 256, 0, stream>>>(x, xb, n4);
  }
  {
    int n4 = DG_DIM * D_DIM / 4;
    cast_f32_bf16<<<(n4 + 255) / 256, 256, 0, stream>>>(w1, w1b, n4);
  }
  {
    int n4 = N2_DIM * DG_DIM / 4;
    cast_permute_w2<<<(n4 + 255) / 256, 256, 0, stream>>>(w2, w2b, n4);
  }

  gemm1_silu<<<dim3(DG_DIM / 128, M_DIM / 128), 256, 0, stream>>>(xb, w1b, hb);
  gemm2_conv_silu<<<dim3(N2_DIM / 128, M_DIM / 128), 256, 0, stream>>>(
      hb, w2b, b2, x, out);
}